// Round 1
// baseline (1824.836 us; speedup 1.0000x reference)
//
#include <hip/hip_runtime.h>
#include <math.h>

namespace {

constexpr int NA  = 50000;
constexpr int NE  = 1600000;
constexpr int NM  = 500;
constexpr int H   = 128;
constexpr int G   = 50;
constexpr int L   = 6;
constexpr int TBL = 4096;
constexpr float DMAX = 6.0f;

__device__ __forceinline__ float sspf(float v) {
    // softplus(v) - ln2, stable
    return fmaxf(v, 0.0f) + log1pf(expf(-fabsf(v))) - 0.6931471805599453f;
}

// ---------------- preprocessing ----------------

__global__ void edge_dist_count(const float* __restrict__ pos, const int* __restrict__ ei,
                                float* __restrict__ ed_raw, int* __restrict__ counts) {
    int e = blockIdx.x * 256 + threadIdx.x;
    if (e >= NE) return;
    int s = ei[e];
    int t = ei[NE + e];
    float dx = pos[3*s]   - pos[3*t];
    float dy = pos[3*s+1] - pos[3*t+1];
    float dz = pos[3*s+2] - pos[3*t+2];
    float d = sqrtf(dx*dx + dy*dy + dz*dz + 1e-12f);
    ed_raw[e] = d;
    if (d < DMAX) atomicAdd(&counts[t], 1);
}

__global__ void scan_counts(const int* __restrict__ counts, int* __restrict__ row_ptr) {
    __shared__ int part[1024];
    int tid = threadIdx.x;
    const int chunk = (NA + 1023) / 1024;  // 49
    int beg = tid * chunk;
    int end = min(beg + chunk, NA);
    int s = 0;
    for (int i = beg; i < end; ++i) s += counts[i];
    part[tid] = s;
    __syncthreads();
    for (int off = 1; off < 1024; off <<= 1) {
        int v = (tid >= off) ? part[tid - off] : 0;
        __syncthreads();
        part[tid] += v;
        __syncthreads();
    }
    int base = (tid == 0) ? 0 : part[tid - 1];
    for (int i = beg; i < end; ++i) { row_ptr[i] = base; base += counts[i]; }
    if (tid == 1023) row_ptr[NA] = part[1023];
}

__global__ void csr_fill(const int* __restrict__ ei, const float* __restrict__ ed_raw,
                         int* __restrict__ cursor, int* __restrict__ esrc,
                         float* __restrict__ ed_csr) {
    int e = blockIdx.x * 256 + threadIdx.x;
    if (e >= NE) return;
    float d = ed_raw[e];
    if (d < DMAX) {
        int t = ei[NE + e];
        int p = atomicAdd(&cursor[t], 1);
        esrc[p] = ei[e];
        ed_csr[p] = d;
    }
}

__global__ void h_init(const int* __restrict__ z, const float* __restrict__ emb,
                       float* __restrict__ h) {
    int idx = blockIdx.x * 256 + threadIdx.x;
    if (idx >= NA * H) return;
    int i = idx >> 7, f = idx & 127;
    h[idx] = emb[(z[i] << 7) + f];
}

// ---------------- per-layer filter table: wtab[t][f] = (ssp(ea(d_t)@iw1+b1)@iw2+b2)[f] * C(d_t) ----------------

__global__ __launch_bounds__(128) void build_table(const float* __restrict__ iw1, const float* __restrict__ ib1,
                                                   const float* __restrict__ iw2, const float* __restrict__ ib2,
                                                   float* __restrict__ wtab) {
    __shared__ float ea[8][G];
    __shared__ float hid[8][H];
    int t0 = blockIdx.x * 8;
    int f = threadIdx.x;
    const float step  = DMAX / (float)(TBL - 1);
    const float sp    = 5.0f / 49.0f;
    const float coeff = -0.5f / (sp * sp);
    for (int idx = f; idx < 8 * G; idx += 128) {
        int r = idx / G, g = idx - r * G;
        float d = (float)(t0 + r) * step;
        float dd = d - (float)g * sp;
        ea[r][g] = expf(coeff * dd * dd);
    }
    __syncthreads();
    float acc[8];
    float b1 = ib1[f];
    #pragma unroll
    for (int r = 0; r < 8; ++r) acc[r] = b1;
    for (int g = 0; g < G; ++g) {
        float w = iw1[g * H + f];
        #pragma unroll
        for (int r = 0; r < 8; ++r) acc[r] += ea[r][g] * w;
    }
    #pragma unroll
    for (int r = 0; r < 8; ++r) hid[r][f] = sspf(acc[r]);
    __syncthreads();
    float o[8];
    float b2 = ib2[f];
    #pragma unroll
    for (int r = 0; r < 8; ++r) o[r] = b2;
    for (int j = 0; j < H; ++j) {
        float w = iw2[j * H + f];
        #pragma unroll
        for (int r = 0; r < 8; ++r) o[r] += hid[r][j] * w;
    }
    #pragma unroll
    for (int r = 0; r < 8; ++r) {
        float d = (float)(t0 + r) * step;
        float C = 0.5f * (cosf(d * (3.14159265358979323846f / 5.0f)) + 1.0f);
        wtab[(t0 + r) * H + f] = o[r] * C;
    }
}

// ---------------- node GEMM: out = [ssp](A@B [+bias]) [+res], B is 128x128 ----------------

template<int ACT, int BIAS, int RES>
__global__ __launch_bounds__(256, 2) void gemm128(const float* __restrict__ A, const float* __restrict__ B,
                                                  const float* __restrict__ bias, const float* __restrict__ res,
                                                  float* __restrict__ out, int M) {
    __shared__ float As[64][132];   // row-major A tile, +4 pad keeps 16B align & kills bank conflicts
    __shared__ float Bs[128][68];   // B columns cb*64..+63, +4 pad
    int tid = threadIdx.x;
    int r0 = blockIdx.x * 64;
    int cb = blockIdx.y;            // 0 or 1 (column half)
    {
        int row = tid >> 5;               // 0..7
        int k0  = (tid & 31) << 2;        // 0..124
        #pragma unroll
        for (int rr = 0; rr < 64; rr += 8) {
            int r = row + rr;
            float4 v = make_float4(0.f, 0.f, 0.f, 0.f);
            if (r0 + r < M) v = *(const float4*)&A[(size_t)(r0 + r) * H + k0];
            *(float4*)&As[r][k0] = v;
        }
        int kb = tid >> 4;                // 0..15
        int c0 = (tid & 15) << 2;         // 0..60
        #pragma unroll
        for (int kk = 0; kk < 128; kk += 16) {
            *(float4*)&Bs[kb + kk][c0] = *(const float4*)&B[(kb + kk) * H + cb * 64 + c0];
        }
    }
    __syncthreads();
    int ty = tid >> 4, tx = tid & 15;
    float acc[4][4] = {};
    #pragma unroll 8
    for (int k = 0; k < 128; ++k) {
        float a0 = As[(ty << 2) + 0][k];
        float a1 = As[(ty << 2) + 1][k];
        float a2 = As[(ty << 2) + 2][k];
        float a3 = As[(ty << 2) + 3][k];
        float4 b = *(const float4*)&Bs[k][tx << 2];
        acc[0][0] += a0 * b.x; acc[0][1] += a0 * b.y; acc[0][2] += a0 * b.z; acc[0][3] += a0 * b.w;
        acc[1][0] += a1 * b.x; acc[1][1] += a1 * b.y; acc[1][2] += a1 * b.z; acc[1][3] += a1 * b.w;
        acc[2][0] += a2 * b.x; acc[2][1] += a2 * b.y; acc[2][2] += a2 * b.z; acc[2][3] += a2 * b.w;
        acc[3][0] += a3 * b.x; acc[3][1] += a3 * b.y; acc[3][2] += a3 * b.z; acc[3][3] += a3 * b.w;
    }
    int colbase = cb * 64 + (tx << 2);
    float4 bv = make_float4(0.f, 0.f, 0.f, 0.f);
    if (BIAS) bv = *(const float4*)&bias[colbase];
    #pragma unroll
    for (int i = 0; i < 4; ++i) {
        int row = r0 + (ty << 2) + i;
        if (row >= M) break;
        float4 v;
        v.x = acc[i][0] + bv.x;
        v.y = acc[i][1] + bv.y;
        v.z = acc[i][2] + bv.z;
        v.w = acc[i][3] + bv.w;
        if (ACT) { v.x = sspf(v.x); v.y = sspf(v.y); v.z = sspf(v.z); v.w = sspf(v.w); }
        if (RES) {
            float4 rv = *(const float4*)&res[(size_t)row * H + colbase];
            v.x += rv.x; v.y += rv.y; v.z += rv.z; v.w += rv.w;
        }
        *(float4*)&out[(size_t)row * H + colbase] = v;
    }
}

// ---------------- edge aggregation: agg[i] = sum_{e->i} x[src_e] * lerp(wtab, d_e) ----------------

__global__ __launch_bounds__(128) void edge_agg(const int* __restrict__ row_ptr, const int* __restrict__ esrc,
                                                const float* __restrict__ ed, const float* __restrict__ x,
                                                const float* __restrict__ wtab, float* __restrict__ agg) {
    int i = blockIdx.x;
    int f = threadIdx.x;
    int p0 = row_ptr[i], p1 = row_ptr[i + 1];
    const float scale = (float)(TBL - 1) / DMAX;
    float acc = 0.f;
    int p = p0;
    for (; p + 2 <= p1; p += 2) {
        int   s0 = esrc[p],     s1 = esrc[p + 1];
        float d0 = ed[p],       d1 = ed[p + 1];
        float u0 = d0 * scale,  u1 = d1 * scale;
        int   i0 = (int)u0,     i1 = (int)u1;
        float t0 = u0 - (float)i0, t1 = u1 - (float)i1;
        float wa0 = wtab[(i0 << 7) + f],       wa1 = wtab[(i1 << 7) + f];
        float wb0 = wtab[(i0 << 7) + 128 + f], wb1 = wtab[(i1 << 7) + 128 + f];
        float xa = x[(s0 << 7) + f], xb = x[(s1 << 7) + f];
        acc += xa * (wa0 + t0 * (wb0 - wa0));
        acc += xb * (wa1 + t1 * (wb1 - wa1));
    }
    if (p < p1) {
        int   s0 = esrc[p];
        float d0 = ed[p];
        float u0 = d0 * scale;
        int   i0 = (int)u0;
        float t0 = u0 - (float)i0;
        float wa0 = wtab[(i0 << 7) + f];
        float wb0 = wtab[(i0 << 7) + 128 + f];
        acc += x[(s0 << 7) + f] * (wa0 + t0 * (wb0 - wa0));
    }
    agg[(i << 7) + f] = acc;
}

// ---------------- readout ----------------

__global__ void mol_reduce(const int* __restrict__ a2c, const int* __restrict__ c2m,
                           const float* __restrict__ h2, float* __restrict__ mol) {
    int idx = blockIdx.x * 256 + threadIdx.x;
    if (idx >= NA * H) return;
    int i = idx >> 7, f = idx & 127;
    int m = c2m[a2c[i]];
    atomicAdd(&mol[(m << 7) + f], h2[idx]);
}

__global__ void final_mlp(const float* __restrict__ mol, const float* __restrict__ h1w,
                          const float* __restrict__ h1b, const float* __restrict__ h2w,
                          const float* __restrict__ h2b, float* __restrict__ out) {
    int m = blockIdx.x;
    int j = threadIdx.x;   // 64 threads = 1 wave
    float acc = h1b[j];
    for (int k = 0; k < H; ++k) acc += mol[(m << 7) + k] * h1w[k * 64 + j];
    float hv = sspf(acc) * h2w[j];
    #pragma unroll
    for (int off = 32; off > 0; off >>= 1) hv += __shfl_down(hv, off);
    if (j == 0) out[m] = hv + h2b[0];
}

} // namespace

extern "C" void kernel_launch(void* const* d_in, const int* in_sizes, int n_in,
                              void* d_out, int out_size, void* d_ws, size_t ws_size,
                              hipStream_t stream) {
    const int*   z    = (const int*)d_in[0];
    const float* pos  = (const float*)d_in[1];
    const int*   ei   = (const int*)d_in[2];
    const int*   a2c  = (const int*)d_in[3];
    const int*   c2m  = (const int*)d_in[4];
    const float* emb  = (const float*)d_in[5];
    const float* iw1  = (const float*)d_in[6];
    const float* ib1  = (const float*)d_in[7];
    const float* iw2  = (const float*)d_in[8];
    const float* ib2  = (const float*)d_in[9];
    const float* il1  = (const float*)d_in[10];
    const float* il2w = (const float*)d_in[11];
    const float* il2b = (const float*)d_in[12];
    const float* ilw  = (const float*)d_in[13];
    const float* ilb  = (const float*)d_in[14];
    const float* l1w  = (const float*)d_in[15];
    const float* l1b  = (const float*)d_in[16];
    const float* l2w  = (const float*)d_in[17];
    const float* l2b  = (const float*)d_in[18];
    const float* h1w  = (const float*)d_in[19];
    const float* h1b  = (const float*)d_in[20];
    const float* h2w  = (const float*)d_in[21];
    const float* h2b  = (const float*)d_in[22];
    float* out = (float*)d_out;
    (void)in_sizes; (void)n_in; (void)out_size; (void)ws_size;

    char* base = (char*)d_ws;
    size_t off = 0;
    auto carve = [&](size_t bytes) -> char* {
        char* p = base + off;
        off += (bytes + 255) & ~(size_t)255;
        return p;
    };
    float* h      = (float*)carve((size_t)NA * H * 4);
    float* xbuf   = (float*)carve((size_t)NA * H * 4);
    float* agg    = (float*)carve((size_t)NA * H * 4);
    float* wtab   = (float*)carve((size_t)TBL * H * 4);
    float* ed_raw = (float*)carve((size_t)NE * 4);
    float* ed_csr = (float*)carve((size_t)NE * 4);
    int*   esrc   = (int*)carve((size_t)NE * 4);
    int*   counts = (int*)carve((size_t)NA * 4);
    int*   rowp   = (int*)carve((size_t)(NA + 1) * 4);
    int*   cursor = (int*)carve((size_t)NA * 4);
    float* mol    = (float*)carve((size_t)NM * H * 4);

    hipMemsetAsync(counts, 0, (size_t)NA * 4, stream);
    edge_dist_count<<<(NE + 255) / 256, 256, 0, stream>>>(pos, ei, ed_raw, counts);
    scan_counts<<<1, 1024, 0, stream>>>(counts, rowp);
    hipMemcpyAsync(cursor, rowp, (size_t)NA * 4, hipMemcpyDeviceToDevice, stream);
    csr_fill<<<(NE + 255) / 256, 256, 0, stream>>>(ei, ed_raw, cursor, esrc, ed_csr);
    h_init<<<(NA * H + 255) / 256, 256, 0, stream>>>(z, emb, h);

    dim3 ggrid((NA + 63) / 64, 2);
    for (int k = 0; k < L; ++k) {
        build_table<<<TBL / 8, 128, 0, stream>>>(iw1 + (size_t)k * G * H, ib1 + (size_t)k * H,
                                                 iw2 + (size_t)k * H * H, ib2 + (size_t)k * H, wtab);
        gemm128<0, 0, 0><<<ggrid, 256, 0, stream>>>(h, il1 + (size_t)k * H * H, nullptr, nullptr, xbuf, NA);
        edge_agg<<<NA, 128, 0, stream>>>(rowp, esrc, ed_csr, xbuf, wtab, agg);
        gemm128<1, 1, 0><<<ggrid, 256, 0, stream>>>(agg, il2w + (size_t)k * H * H, il2b + (size_t)k * H,
                                                    nullptr, xbuf, NA);
        gemm128<0, 1, 1><<<ggrid, 256, 0, stream>>>(xbuf, ilw + (size_t)k * H * H, ilb + (size_t)k * H,
                                                    h, h, NA);
    }
    gemm128<1, 1, 0><<<ggrid, 256, 0, stream>>>(h, l1w, l1b, nullptr, xbuf, NA);
    gemm128<0, 1, 0><<<ggrid, 256, 0, stream>>>(xbuf, l2w, l2b, nullptr, agg, NA);
    hipMemsetAsync(mol, 0, (size_t)NM * H * 4, stream);
    mol_reduce<<<(NA * H + 255) / 256, 256, 0, stream>>>(a2c, c2m, agg, mol);
    final_mlp<<<NM, 64, 0, stream>>>(mol, h1w, h1b, h2w, h2b, out);
}

// Round 2
// 1814.840 us; speedup vs baseline: 1.0055x; 1.0055x over previous
//
#include <hip/hip_runtime.h>
#include <math.h>

namespace {

constexpr int NA  = 50000;
constexpr int NE  = 1600000;
constexpr int NM  = 500;
constexpr int H   = 128;
constexpr int G   = 50;
constexpr int L   = 6;
constexpr int TBL = 4096;
constexpr float DMAX = 6.0f;
constexpr int NSCAN = (NA + 255) / 256;   // 196

__device__ __forceinline__ float sspf(float v) {
    return fmaxf(v, 0.0f) + log1pf(expf(-fabsf(v))) - 0.6931471805599453f;
}
__device__ __forceinline__ float bf16lo(unsigned v) { return __uint_as_float(v << 16); }
__device__ __forceinline__ float bf16hi(unsigned v) { return __uint_as_float(v & 0xffff0000u); }
__device__ __forceinline__ unsigned f2bf(float f) {
    unsigned u = __float_as_uint(f);
    return (u + 0x7fffu + ((u >> 16) & 1u)) >> 16;
}

// ---------------- preprocessing ----------------

__global__ void edge_count(const float* __restrict__ pos, const int* __restrict__ ei,
                           int* __restrict__ counts) {
    int e = blockIdx.x * 256 + threadIdx.x;
    if (e >= NE) return;
    int s = ei[e], t = ei[NE + e];
    float dx = pos[3*s]   - pos[3*t];
    float dy = pos[3*s+1] - pos[3*t+1];
    float dz = pos[3*s+2] - pos[3*t+2];
    float d = sqrtf(dx*dx + dy*dy + dz*dz + 1e-12f);
    float u = d * ((float)(TBL - 1) / DMAX);
    if (u < (float)(TBL - 1)) atomicAdd(&counts[t], 1);
}

__global__ void scan_part(const int* __restrict__ counts, int* __restrict__ bsum) {
    __shared__ int sh[256];
    int i = blockIdx.x * 256 + threadIdx.x;
    int v = (i < NA) ? counts[i] : 0;
    sh[threadIdx.x] = v;
    __syncthreads();
    for (int off = 128; off > 0; off >>= 1) {
        if (threadIdx.x < off) sh[threadIdx.x] += sh[threadIdx.x + off];
        __syncthreads();
    }
    if (threadIdx.x == 0) bsum[blockIdx.x] = sh[0];
}

__global__ void scan_top(int* __restrict__ bsum, int* __restrict__ rowp) {
    __shared__ int sh[256];
    int t = threadIdx.x;
    int v = (t < NSCAN) ? bsum[t] : 0;
    sh[t] = v;
    __syncthreads();
    for (int off = 1; off < 256; off <<= 1) {
        int u = (t >= off) ? sh[t - off] : 0;
        __syncthreads();
        sh[t] += u;
        __syncthreads();
    }
    if (t < NSCAN) bsum[t] = sh[t] - v;   // exclusive block offset
    if (t == 255) rowp[NA] = sh[255];
}

__global__ void scan_write(const int* __restrict__ counts, const int* __restrict__ bsum,
                           int* __restrict__ rowp) {
    __shared__ int sh[256];
    int b = blockIdx.x, t = threadIdx.x;
    int i = b * 256 + t;
    int v = (i < NA) ? counts[i] : 0;
    sh[t] = v;
    __syncthreads();
    for (int off = 1; off < 256; off <<= 1) {
        int u = (t >= off) ? sh[t - off] : 0;
        __syncthreads();
        sh[t] += u;
        __syncthreads();
    }
    if (i < NA) rowp[i] = bsum[b] + sh[t] - v;
}

__global__ void csr_fill(const float* __restrict__ pos, const int* __restrict__ ei,
                         int* __restrict__ cursor, int* __restrict__ esrc,
                         float* __restrict__ edu) {
    int e = blockIdx.x * 256 + threadIdx.x;
    if (e >= NE) return;
    int s = ei[e], t = ei[NE + e];
    float dx = pos[3*s]   - pos[3*t];
    float dy = pos[3*s+1] - pos[3*t+1];
    float dz = pos[3*s+2] - pos[3*t+2];
    float d = sqrtf(dx*dx + dy*dy + dz*dz + 1e-12f);
    float u = d * ((float)(TBL - 1) / DMAX);
    if (u < (float)(TBL - 1)) {
        int p = atomicAdd(&cursor[t], 1);
        esrc[p] = s;
        edu[p] = u;
    }
}

__global__ void h_init(const int* __restrict__ z, const float* __restrict__ emb,
                       float* __restrict__ h) {
    int idx = blockIdx.x * 256 + threadIdx.x;
    if (idx >= NA * H) return;
    int i = idx >> 7, f = idx & 127;
    h[idx] = emb[(z[i] << 7) + f];
}

// ---------------- filter tables (all L layers, one launch) ----------------

__global__ __launch_bounds__(128) void build_table(const float* __restrict__ iw1, const float* __restrict__ ib1,
                                                   const float* __restrict__ iw2, const float* __restrict__ ib2,
                                                   float* __restrict__ wtab) {
    int l = blockIdx.y;
    iw1 += (size_t)l * G * H; ib1 += (size_t)l * H;
    iw2 += (size_t)l * H * H; ib2 += (size_t)l * H;
    wtab += (size_t)l * TBL * H;
    __shared__ float ea[8][G];
    __shared__ float hid[8][H];
    int t0 = blockIdx.x * 8;
    int f = threadIdx.x;
    const float step  = DMAX / (float)(TBL - 1);
    const float sp    = 5.0f / 49.0f;
    const float coeff = -0.5f / (sp * sp);
    for (int idx = f; idx < 8 * G; idx += 128) {
        int r = idx / G, g = idx - r * G;
        float d = (float)(t0 + r) * step;
        float dd = d - (float)g * sp;
        ea[r][g] = expf(coeff * dd * dd);
    }
    __syncthreads();
    float acc[8];
    float b1 = ib1[f];
    #pragma unroll
    for (int r = 0; r < 8; ++r) acc[r] = b1;
    for (int g = 0; g < G; ++g) {
        float w = iw1[g * H + f];
        #pragma unroll
        for (int r = 0; r < 8; ++r) acc[r] += ea[r][g] * w;
    }
    #pragma unroll
    for (int r = 0; r < 8; ++r) hid[r][f] = sspf(acc[r]);
    __syncthreads();
    float o[8];
    float b2 = ib2[f];
    #pragma unroll
    for (int r = 0; r < 8; ++r) o[r] = b2;
    for (int j = 0; j < H; ++j) {
        float w = iw2[j * H + f];
        #pragma unroll
        for (int r = 0; r < 8; ++r) o[r] += hid[r][j] * w;
    }
    #pragma unroll
    for (int r = 0; r < 8; ++r) {
        float d = (float)(t0 + r) * step;
        float C = 0.5f * (cosf(d * (3.14159265358979323846f / 5.0f)) + 1.0f);
        wtab[(size_t)(t0 + r) * H + f] = o[r] * C;
    }
}

// ---------------- node GEMM: A(Mx128) @ B(128x128); B in LDS, A streamed to regs ----------------

template<int ACT, int BIAS, int RES, int OBF16>
__global__ __launch_bounds__(256, 4) void gemm_rs(const float* __restrict__ A, const float* __restrict__ B,
                                                  const float* __restrict__ bias, const float* __restrict__ res,
                                                  float* __restrict__ out, unsigned short* __restrict__ outb,
                                                  int M) {
    __shared__ float Bs[128][68];
    int tid = threadIdx.x;
    int col0 = blockIdx.y << 6;           // column half: 0 or 64
    for (int idx = tid; idx < 128 * 16; idx += 256) {
        int r = idx >> 4, c4 = (idx & 15) << 2;
        *(float4*)&Bs[r][c4] = *(const float4*)&B[(r << 7) + col0 + c4];
    }
    __syncthreads();
    int rg = tid >> 4, cg = tid & 15;
    int row0 = (blockIdx.x << 6) + (rg << 2);
    const float* a0 = A + (size_t)min(row0 + 0, M - 1) * H;
    const float* a1 = A + (size_t)min(row0 + 1, M - 1) * H;
    const float* a2 = A + (size_t)min(row0 + 2, M - 1) * H;
    const float* a3 = A + (size_t)min(row0 + 3, M - 1) * H;
    int c = cg << 2;
    float acc[4][4] = {};
    float4 n0 = *(const float4*)a0;
    float4 n1 = *(const float4*)a1;
    float4 n2 = *(const float4*)a2;
    float4 n3 = *(const float4*)a3;
    #pragma unroll 2
    for (int k4 = 0; k4 < 32; ++k4) {
        float4 c0 = n0, c1 = n1, c2 = n2, c3 = n3;
        if (k4 < 31) {
            n0 = *(const float4*)(a0 + ((k4 + 1) << 2));
            n1 = *(const float4*)(a1 + ((k4 + 1) << 2));
            n2 = *(const float4*)(a2 + ((k4 + 1) << 2));
            n3 = *(const float4*)(a3 + ((k4 + 1) << 2));
        }
        #pragma unroll
        for (int kk = 0; kk < 4; ++kk) {
            float4 b = *(const float4*)&Bs[(k4 << 2) + kk][c];
            float e0 = ((const float*)&c0)[kk];
            float e1 = ((const float*)&c1)[kk];
            float e2 = ((const float*)&c2)[kk];
            float e3 = ((const float*)&c3)[kk];
            acc[0][0] += e0 * b.x; acc[0][1] += e0 * b.y; acc[0][2] += e0 * b.z; acc[0][3] += e0 * b.w;
            acc[1][0] += e1 * b.x; acc[1][1] += e1 * b.y; acc[1][2] += e1 * b.z; acc[1][3] += e1 * b.w;
            acc[2][0] += e2 * b.x; acc[2][1] += e2 * b.y; acc[2][2] += e2 * b.z; acc[2][3] += e2 * b.w;
            acc[3][0] += e3 * b.x; acc[3][1] += e3 * b.y; acc[3][2] += e3 * b.z; acc[3][3] += e3 * b.w;
        }
    }
    float4 bv = make_float4(0.f, 0.f, 0.f, 0.f);
    if (BIAS) bv = *(const float4*)&bias[col0 + c];
    #pragma unroll
    for (int i = 0; i < 4; ++i) {
        int row = row0 + i;
        if (row >= M) break;
        float v0 = acc[i][0] + bv.x, v1 = acc[i][1] + bv.y;
        float v2 = acc[i][2] + bv.z, v3 = acc[i][3] + bv.w;
        if (ACT) { v0 = sspf(v0); v1 = sspf(v1); v2 = sspf(v2); v3 = sspf(v3); }
        if (RES) {
            float4 rv = *(const float4*)&res[(size_t)row * H + col0 + c];
            v0 += rv.x; v1 += rv.y; v2 += rv.z; v3 += rv.w;
        }
        if (OBF16) {
            unsigned lo = f2bf(v0) | (f2bf(v1) << 16);
            unsigned hi = f2bf(v2) | (f2bf(v3) << 16);
            *(uint2*)&outb[(size_t)row * H + col0 + c] = make_uint2(lo, hi);
        } else {
            *(float4*)&out[(size_t)row * H + col0 + c] = make_float4(v0, v1, v2, v3);
        }
    }
}

// ---------------- edge aggregation: one wave per atom, 2 feats/lane, bf16 x-gather ----------------

__global__ __launch_bounds__(256) void edge_agg(const int* __restrict__ rowp, const int* __restrict__ esrc,
                                                const float* __restrict__ edu, const unsigned short* __restrict__ xb,
                                                const float* __restrict__ wtab, float* __restrict__ agg) {
    int wv = threadIdx.x >> 6, ln = threadIdx.x & 63;
    int i = (blockIdx.x << 2) + wv;
    if (i >= NA) return;
    int p0 = rowp[i], p1 = rowp[i + 1];
    int f2 = ln << 1;
    float ax = 0.f, ay = 0.f;
    int p = p0;
    for (; p + 2 <= p1; p += 2) {
        int   s0 = esrc[p],  s1 = esrc[p + 1];
        float u0 = edu[p],   u1 = edu[p + 1];
        int   i0 = (int)u0,  i1 = (int)u1;
        float t0 = u0 - (float)i0, t1 = u1 - (float)i1;
        unsigned xv0 = *(const unsigned*)&xb[(s0 << 7) + f2];
        unsigned xv1 = *(const unsigned*)&xb[(s1 << 7) + f2];
        float2 wa0 = *(const float2*)&wtab[(i0 << 7) + f2];
        float2 wb0 = *(const float2*)&wtab[((i0 + 1) << 7) + f2];
        float2 wa1 = *(const float2*)&wtab[(i1 << 7) + f2];
        float2 wb1 = *(const float2*)&wtab[((i1 + 1) << 7) + f2];
        ax += bf16lo(xv0) * (wa0.x + t0 * (wb0.x - wa0.x));
        ay += bf16hi(xv0) * (wa0.y + t0 * (wb0.y - wa0.y));
        ax += bf16lo(xv1) * (wa1.x + t1 * (wb1.x - wa1.x));
        ay += bf16hi(xv1) * (wa1.y + t1 * (wb1.y - wa1.y));
    }
    if (p < p1) {
        int   s0 = esrc[p];
        float u0 = edu[p];
        int   i0 = (int)u0;
        float t0 = u0 - (float)i0;
        unsigned xv0 = *(const unsigned*)&xb[(s0 << 7) + f2];
        float2 wa0 = *(const float2*)&wtab[(i0 << 7) + f2];
        float2 wb0 = *(const float2*)&wtab[((i0 + 1) << 7) + f2];
        ax += bf16lo(xv0) * (wa0.x + t0 * (wb0.x - wa0.x));
        ay += bf16hi(xv0) * (wa0.y + t0 * (wb0.y - wa0.y));
    }
    *(float2*)&agg[(i << 7) + f2] = make_float2(ax, ay);
}

// ---------------- readout ----------------

__global__ void mol_bounds(const int* __restrict__ a2c, const int* __restrict__ c2m,
                           int* __restrict__ ms, int* __restrict__ me) {
    int i = blockIdx.x * 256 + threadIdx.x;
    if (i >= NA) return;
    int m = c2m[a2c[i]];
    int mp = (i == 0) ? -1 : c2m[a2c[i - 1]];
    if (m != mp) ms[m] = i;
    int mn = (i == NA - 1) ? -1 : c2m[a2c[i + 1]];
    if (m != mn) me[m] = i + 1;
}

__global__ void mol_sum(const int* __restrict__ ms, const int* __restrict__ me,
                        const float* __restrict__ h2, float* __restrict__ mol) {
    int m = blockIdx.x, f = threadIdx.x;   // 128 threads
    float acc = 0.f;
    int e0 = ms[m], e1 = me[m];
    for (int i = e0; i < e1; ++i) acc += h2[(i << 7) + f];
    mol[(m << 7) + f] = acc;
}

__global__ void final_mlp(const float* __restrict__ mol, const float* __restrict__ h1w,
                          const float* __restrict__ h1b, const float* __restrict__ h2w,
                          const float* __restrict__ h2b, float* __restrict__ out) {
    int m = blockIdx.x;
    int j = threadIdx.x;   // 64 threads = 1 wave
    float acc = h1b[j];
    for (int k = 0; k < H; ++k) acc += mol[(m << 7) + k] * h1w[k * 64 + j];
    float hv = sspf(acc) * h2w[j];
    #pragma unroll
    for (int off = 32; off > 0; off >>= 1) hv += __shfl_down(hv, off);
    if (j == 0) out[m] = hv + h2b[0];
}

} // namespace

extern "C" void kernel_launch(void* const* d_in, const int* in_sizes, int n_in,
                              void* d_out, int out_size, void* d_ws, size_t ws_size,
                              hipStream_t stream) {
    const int*   z    = (const int*)d_in[0];
    const float* pos  = (const float*)d_in[1];
    const int*   ei   = (const int*)d_in[2];
    const int*   a2c  = (const int*)d_in[3];
    const int*   c2m  = (const int*)d_in[4];
    const float* emb  = (const float*)d_in[5];
    const float* iw1  = (const float*)d_in[6];
    const float* ib1  = (const float*)d_in[7];
    const float* iw2  = (const float*)d_in[8];
    const float* ib2  = (const float*)d_in[9];
    const float* il1  = (const float*)d_in[10];
    const float* il2w = (const float*)d_in[11];
    const float* il2b = (const float*)d_in[12];
    const float* ilw  = (const float*)d_in[13];
    const float* ilb  = (const float*)d_in[14];
    const float* l1w  = (const float*)d_in[15];
    const float* l1b  = (const float*)d_in[16];
    const float* l2w  = (const float*)d_in[17];
    const float* l2b  = (const float*)d_in[18];
    const float* h1w  = (const float*)d_in[19];
    const float* h1b  = (const float*)d_in[20];
    const float* h2w  = (const float*)d_in[21];
    const float* h2b  = (const float*)d_in[22];
    float* out = (float*)d_out;
    (void)in_sizes; (void)n_in; (void)out_size; (void)ws_size;

    char* base = (char*)d_ws;
    size_t off = 0;
    auto carve = [&](size_t bytes) -> char* {
        char* p = base + off;
        off += (bytes + 255) & ~(size_t)255;
        return p;
    };
    float* h     = (float*)carve((size_t)NA * H * 4);
    float* xbuf  = (float*)carve((size_t)NA * H * 4);
    float* agg   = (float*)carve((size_t)NA * H * 4);
    float* wtab  = (float*)carve((size_t)L * TBL * H * 4);
    float* edu   = (float*)carve((size_t)NE * 4);
    int*   esrc  = (int*)carve((size_t)NE * 4);
    int*   counts= (int*)carve((size_t)NA * 4);       // reused as cursor after scan
    int*   rowp  = (int*)carve((size_t)(NA + 1) * 4);
    int*   bsum  = (int*)carve((size_t)NSCAN * 4);
    int*   ms    = (int*)carve((size_t)NM * 4);
    int*   me    = (int*)carve((size_t)NM * 4);
    float* mol   = (float*)carve((size_t)NM * H * 4);
    unsigned short* xb = (unsigned short*)xbuf;       // alias: x(bf16) dead before xbuf is written

    hipMemsetAsync(counts, 0, (size_t)NA * 4, stream);
    edge_count<<<NE / 256, 256, 0, stream>>>(pos, ei, counts);
    scan_part<<<NSCAN, 256, 0, stream>>>(counts, bsum);
    scan_top<<<1, 256, 0, stream>>>(bsum, rowp);
    scan_write<<<NSCAN, 256, 0, stream>>>(counts, bsum, rowp);
    hipMemcpyAsync(counts, rowp, (size_t)NA * 4, hipMemcpyDeviceToDevice, stream); // counts := cursor
    csr_fill<<<NE / 256, 256, 0, stream>>>(pos, ei, counts, esrc, edu);
    h_init<<<(NA * H) / 256, 256, 0, stream>>>(z, emb, h);
    build_table<<<dim3(TBL / 8, L), 128, 0, stream>>>(iw1, ib1, iw2, ib2, wtab);

    dim3 ggrid((NA + 63) / 64, 2);
    for (int k = 0; k < L; ++k) {
        gemm_rs<0, 0, 0, 1><<<ggrid, 256, 0, stream>>>(h, il1 + (size_t)k * H * H, nullptr, nullptr,
                                                       nullptr, xb, NA);
        edge_agg<<<(NA + 3) / 4, 256, 0, stream>>>(rowp, esrc, edu, xb, wtab + (size_t)k * TBL * H, agg);
        gemm_rs<1, 1, 0, 0><<<ggrid, 256, 0, stream>>>(agg, il2w + (size_t)k * H * H, il2b + (size_t)k * H,
                                                       nullptr, xbuf, nullptr, NA);
        gemm_rs<0, 1, 1, 0><<<ggrid, 256, 0, stream>>>(xbuf, ilw + (size_t)k * H * H, ilb + (size_t)k * H,
                                                       h, h, nullptr, NA);
    }
    gemm_rs<1, 1, 0, 0><<<ggrid, 256, 0, stream>>>(h, l1w, l1b, nullptr, xbuf, nullptr, NA);
    gemm_rs<0, 1, 0, 0><<<ggrid, 256, 0, stream>>>(xbuf, l2w, l2b, nullptr, agg, nullptr, NA);

    hipMemsetAsync(ms, 0, (size_t)NM * 4, stream);
    hipMemsetAsync(me, 0, (size_t)NM * 4, stream);
    mol_bounds<<<(NA + 255) / 256, 256, 0, stream>>>(a2c, c2m, ms, me);
    mol_sum<<<NM, 128, 0, stream>>>(ms, me, agg, mol);
    final_mlp<<<NM, 64, 0, stream>>>(mol, h1w, h1b, h2w, h2b, out);
}

// Round 3
// 1181.415 us; speedup vs baseline: 1.5446x; 1.5362x over previous
//
#include <hip/hip_runtime.h>
#include <math.h>

namespace {

constexpr int NA  = 50000;
constexpr int NE  = 1600000;
constexpr int NM  = 500;
constexpr int H   = 128;
constexpr int G   = 50;
constexpr int L   = 6;
constexpr int TBL = 8192;
constexpr float DMAX = 6.0f;
constexpr int NSCAN = (NA + 255) / 256;   // 196

typedef _Float16 half8 __attribute__((ext_vector_type(8)));
typedef float f32x4 __attribute__((ext_vector_type(4)));
struct h2 { _Float16 x, y; };

__device__ __forceinline__ float sspf(float v) {
    return fmaxf(v, 0.0f) + log1pf(expf(-fabsf(v))) - 0.6931471805599453f;
}
__device__ __forceinline__ unsigned short f2h(float f) {
    _Float16 h = (_Float16)f;
    return __builtin_bit_cast(unsigned short, h);
}
__device__ __forceinline__ half8 cvt8(float4 a, float4 b) {
    half8 r;
    r[0] = (_Float16)a.x; r[1] = (_Float16)a.y; r[2] = (_Float16)a.z; r[3] = (_Float16)a.w;
    r[4] = (_Float16)b.x; r[5] = (_Float16)b.y; r[6] = (_Float16)b.z; r[7] = (_Float16)b.w;
    return r;
}
// B^T LDS granule offset with XOR swizzle (row stride 256B would be 16-way conflict; G4)
__device__ __forceinline__ int bofs(int nrow, int g) {   // g = 16B granule 0..15, returns u16 index
    int gs = (g & 8) | ((g ^ nrow) & 7);
    return nrow * 128 + gs * 8;
}
__device__ __forceinline__ void stageB(const unsigned short* __restrict__ Bt,
                                       unsigned short* Bs, int tid) {
    for (int i = tid; i < 2048; i += 256) {
        int row = i >> 4, g = i & 15;
        *(uint4*)&Bs[bofs(row, g)] = *(const uint4*)&Bt[i * 8];
    }
}

// ---------------- preprocessing ----------------

__global__ void edge_count(const float* __restrict__ pos, const int* __restrict__ ei,
                           int* __restrict__ counts, int* __restrict__ tt,
                           int* __restrict__ ts, int* __restrict__ tidx) {
    int e = blockIdx.x * 256 + threadIdx.x;
    if (e >= NE) return;
    int s = ei[e], t = ei[NE + e];
    float dx = pos[3*s]   - pos[3*t];
    float dy = pos[3*s+1] - pos[3*t+1];
    float dz = pos[3*s+2] - pos[3*t+2];
    float d = sqrtf(dx*dx + dy*dy + dz*dz + 1e-12f);
    float u = d * ((float)(TBL - 1) / DMAX);
    int idx = -1;
    if (u < (float)(TBL - 1)) {
        idx = (int)(u + 0.5f);
        atomicAdd(&counts[t], 1);
    }
    tt[e] = t; ts[e] = s; tidx[e] = idx;
}

__global__ void scan_part(const int* __restrict__ counts, int* __restrict__ bsum) {
    __shared__ int sh[256];
    int i = blockIdx.x * 256 + threadIdx.x;
    sh[threadIdx.x] = (i < NA) ? counts[i] : 0;
    __syncthreads();
    for (int off = 128; off > 0; off >>= 1) {
        if (threadIdx.x < off) sh[threadIdx.x] += sh[threadIdx.x + off];
        __syncthreads();
    }
    if (threadIdx.x == 0) bsum[blockIdx.x] = sh[0];
}

__global__ void scan_top(int* __restrict__ bsum, int* __restrict__ rowp) {
    __shared__ int sh[256];
    int t = threadIdx.x;
    int v = (t < NSCAN) ? bsum[t] : 0;
    sh[t] = v;
    __syncthreads();
    for (int off = 1; off < 256; off <<= 1) {
        int u = (t >= off) ? sh[t - off] : 0;
        __syncthreads();
        sh[t] += u;
        __syncthreads();
    }
    if (t < NSCAN) bsum[t] = sh[t] - v;
    if (t == 255) rowp[NA] = sh[255];
}

__global__ void scan_write(const int* __restrict__ counts, const int* __restrict__ bsum,
                           int* __restrict__ rowp) {
    __shared__ int sh[256];
    int b = blockIdx.x, t = threadIdx.x;
    int i = b * 256 + t;
    int v = (i < NA) ? counts[i] : 0;
    sh[t] = v;
    __syncthreads();
    for (int off = 1; off < 256; off <<= 1) {
        int u = (t >= off) ? sh[t - off] : 0;
        __syncthreads();
        sh[t] += u;
        __syncthreads();
    }
    if (i < NA) rowp[i] = bsum[b] + sh[t] - v;
}

__global__ void csr_fill(const int* __restrict__ tt, const int* __restrict__ ts,
                         const int* __restrict__ tidx, int* __restrict__ cursor,
                         uint2* __restrict__ meta) {
    int e = blockIdx.x * 256 + threadIdx.x;
    if (e >= NE) return;
    int idx = tidx[e];
    if (idx < 0) return;
    int t = tt[e];
    int p = atomicAdd(&cursor[t], 1);
    meta[p] = make_uint2((unsigned)(ts[e] << 7), (unsigned)(idx << 7));
}

__global__ void h_init(const int* __restrict__ z, const float* __restrict__ emb,
                       float* __restrict__ h) {
    int idx = blockIdx.x * 256 + threadIdx.x;
    if (idx >= NA * H) return;
    int i = idx >> 7, f = idx & 127;
    h[idx] = emb[(z[i] << 7) + f];
}

// f32 [K][N] -> f16 B^T [N][K] (per matrix, blockIdx.y = matrix index)
__global__ void convT(const float* __restrict__ src, unsigned short* __restrict__ dst) {
    int m = blockIdx.y;
    int e = blockIdx.x * 256 + threadIdx.x;   // e = n*128 + k
    int n = e >> 7, k = e & 127;
    dst[(size_t)m * 16384 + e] = f2h(src[(size_t)m * 16384 + k * 128 + n]);
}

// ---------------- filter tables: f16, nearest-sample, all layers ----------------

__global__ __launch_bounds__(128) void build_table(const float* __restrict__ iw1, const float* __restrict__ ib1,
                                                   const float* __restrict__ iw2, const float* __restrict__ ib2,
                                                   unsigned short* __restrict__ wtab) {
    int l = blockIdx.y;
    iw1 += (size_t)l * G * H; ib1 += (size_t)l * H;
    iw2 += (size_t)l * H * H; ib2 += (size_t)l * H;
    wtab += (size_t)l * TBL * H;
    __shared__ float ea[8][G];
    __shared__ float hid[8][H];
    int t0 = blockIdx.x * 8;
    int f = threadIdx.x;
    const float step  = DMAX / (float)(TBL - 1);
    const float sp    = 5.0f / 49.0f;
    const float coeff = -0.5f / (sp * sp);
    for (int idx = f; idx < 8 * G; idx += 128) {
        int r = idx / G, g = idx - r * G;
        float d = (float)(t0 + r) * step;
        float dd = d - (float)g * sp;
        ea[r][g] = expf(coeff * dd * dd);
    }
    __syncthreads();
    float acc[8];
    float b1 = ib1[f];
    #pragma unroll
    for (int r = 0; r < 8; ++r) acc[r] = b1;
    for (int g = 0; g < G; ++g) {
        float w = iw1[g * H + f];
        #pragma unroll
        for (int r = 0; r < 8; ++r) acc[r] += ea[r][g] * w;
    }
    #pragma unroll
    for (int r = 0; r < 8; ++r) hid[r][f] = sspf(acc[r]);
    __syncthreads();
    float o[8];
    float b2 = ib2[f];
    #pragma unroll
    for (int r = 0; r < 8; ++r) o[r] = b2;
    for (int j = 0; j < H; ++j) {
        float w = iw2[j * H + f];
        #pragma unroll
        for (int r = 0; r < 8; ++r) o[r] += hid[r][j] * w;
    }
    #pragma unroll
    for (int r = 0; r < 8; ++r) {
        float d = (float)(t0 + r) * step;
        float C = 0.5f * (cosf(d * (3.14159265358979323846f / 5.0f)) + 1.0f);
        wtab[(size_t)(t0 + r) * H + f] = f2h(o[r] * C);
    }
}

// ---------------- standalone x = f16(h @ B)  (layer 0 only) ----------------

__global__ __launch_bounds__(256) void gemm_xonly(const float* __restrict__ A,
                                                  const unsigned short* __restrict__ Bt,
                                                  unsigned short* __restrict__ xout, int M) {
    __shared__ unsigned short Bs[16384];
    int tid = threadIdx.x;
    int w = tid >> 6, lane = tid & 63, lr = lane & 15, lq = lane >> 4;
    int r0 = blockIdx.x * 64 + w * 16;
    stageB(Bt, Bs, tid);
    const float* arow = A + (size_t)min(r0 + lr, M - 1) * H;
    half8 af[4];
    #pragma unroll
    for (int ks = 0; ks < 4; ++ks)
        af[ks] = cvt8(*(const float4*)(arow + ks * 32 + lq * 8),
                      *(const float4*)(arow + ks * 32 + lq * 8 + 4));
    __syncthreads();
    #pragma unroll
    for (int n = 0; n < 8; ++n) {
        f32x4 acc = {0.f, 0.f, 0.f, 0.f};
        #pragma unroll
        for (int ks = 0; ks < 4; ++ks) {
            half8 bf = *(const half8*)&Bs[bofs(n * 16 + lr, ks * 4 + lq)];
            acc = __builtin_amdgcn_mfma_f32_16x16x32_f16(af[ks], bf, acc, 0, 0, 0);
        }
        #pragma unroll
        for (int j = 0; j < 4; ++j) {
            int row = r0 + 4 * lq + j;
            if (row < M) xout[(size_t)row * H + n * 16 + lr] = f2h(acc[j]);
        }
    }
}

// ---------------- fused node update ----------------
// pass A: t = ssp(Ain @ B1 + bias1)          (t -> LDS f16)
// pass B: hout = [hres +] t @ B2 + bias2     (and h f16 -> LDS if HASX)
// pass C: xout = f16(h @ B3)                 (if HASX)

template<int RES, int HASX>
__global__ __launch_bounds__(256) void node_fused(const float* __restrict__ Ain,
                                                  const float* __restrict__ bias1,
                                                  const unsigned short* __restrict__ B1t,
                                                  const float* __restrict__ hres,
                                                  float* __restrict__ hout,
                                                  const float* __restrict__ bias2,
                                                  const unsigned short* __restrict__ B2t,
                                                  const unsigned short* __restrict__ B3t,
                                                  unsigned short* __restrict__ xout, int M) {
    __shared__ unsigned short Bs[16384];       // 32 KB, reused per pass
    __shared__ _Float16 Ts[64 * 136];          // 17 KB, t then h (f16), +8 pad per row
    int tid = threadIdx.x;
    int w = tid >> 6, lane = tid & 63, lr = lane & 15, lq = lane >> 4;
    int r0 = blockIdx.x * 64 + w * 16;
    int trow = w * 16;

    stageB(B1t, Bs, tid);
    const float* arow = Ain + (size_t)min(r0 + lr, M - 1) * H;
    half8 af[4];
    #pragma unroll
    for (int ks = 0; ks < 4; ++ks)
        af[ks] = cvt8(*(const float4*)(arow + ks * 32 + lq * 8),
                      *(const float4*)(arow + ks * 32 + lq * 8 + 4));
    __syncthreads();

    // ---- pass A ----
    #pragma unroll
    for (int n = 0; n < 8; ++n) {
        f32x4 acc = {0.f, 0.f, 0.f, 0.f};
        #pragma unroll
        for (int ks = 0; ks < 4; ++ks) {
            half8 bf = *(const half8*)&Bs[bofs(n * 16 + lr, ks * 4 + lq)];
            acc = __builtin_amdgcn_mfma_f32_16x16x32_f16(af[ks], bf, acc, 0, 0, 0);
        }
        float b = bias1[n * 16 + lr];
        #pragma unroll
        for (int j = 0; j < 4; ++j)
            Ts[(trow + 4 * lq + j) * 136 + n * 16 + lr] = (_Float16)sspf(acc[j] + b);
    }
    __syncthreads();
    stageB(B2t, Bs, tid);
    half8 tf[4];
    #pragma unroll
    for (int ks = 0; ks < 4; ++ks)
        tf[ks] = *(const half8*)&Ts[(trow + lr) * 136 + ks * 32 + lq * 8];
    __syncthreads();

    // ---- pass B ----
    #pragma unroll
    for (int n = 0; n < 8; ++n) {
        f32x4 acc = {0.f, 0.f, 0.f, 0.f};
        #pragma unroll
        for (int ks = 0; ks < 4; ++ks) {
            half8 bf = *(const half8*)&Bs[bofs(n * 16 + lr, ks * 4 + lq)];
            acc = __builtin_amdgcn_mfma_f32_16x16x32_f16(tf[ks], bf, acc, 0, 0, 0);
        }
        float b = bias2[n * 16 + lr];
        #pragma unroll
        for (int j = 0; j < 4; ++j) {
            int row = r0 + 4 * lq + j;
            float v = acc[j] + b;
            if (RES) v += hres[(size_t)min(row, M - 1) * H + n * 16 + lr];
            if (row < M) hout[(size_t)row * H + n * 16 + lr] = v;
            if (HASX) Ts[(trow + 4 * lq + j) * 136 + n * 16 + lr] = (_Float16)v;
        }
    }

    // ---- pass C ----
    if (HASX) {
        __syncthreads();
        stageB(B3t, Bs, tid);
        half8 hf[4];
        #pragma unroll
        for (int ks = 0; ks < 4; ++ks)
            hf[ks] = *(const half8*)&Ts[(trow + lr) * 136 + ks * 32 + lq * 8];
        __syncthreads();
        #pragma unroll
        for (int n = 0; n < 8; ++n) {
            f32x4 acc = {0.f, 0.f, 0.f, 0.f};
            #pragma unroll
            for (int ks = 0; ks < 4; ++ks) {
                half8 bf = *(const half8*)&Bs[bofs(n * 16 + lr, ks * 4 + lq)];
                acc = __builtin_amdgcn_mfma_f32_16x16x32_f16(hf[ks], bf, acc, 0, 0, 0);
            }
            #pragma unroll
            for (int j = 0; j < 4; ++j) {
                int row = r0 + 4 * lq + j;
                if (row < M) xout[(size_t)row * H + n * 16 + lr] = f2h(acc[j]);
            }
        }
    }
}

// ---------------- edge aggregation: 2 waves/atom, f16 nearest table ----------------

__global__ __launch_bounds__(256) void edge_agg(const int* __restrict__ rowp,
                                                const uint2* __restrict__ meta,
                                                const unsigned short* __restrict__ x,
                                                const unsigned short* __restrict__ wt,
                                                float* __restrict__ agg) {
    __shared__ float2 part[2][64];
    int wv = threadIdx.x >> 6, ln = threadIdx.x & 63;
    int slot = wv >> 1, half = wv & 1;
    int i = (blockIdx.x << 1) + slot;
    int p0 = rowp[i], p1 = rowp[i + 1];
    int f2 = ln << 1;
    float ax = 0.f, ay = 0.f;
    int p = p0 + half;
    for (; p + 2 < p1; p += 4) {
        uint2 m0 = meta[p], m1 = meta[p + 2];
        h2 xv0 = *(const h2*)(x + m0.x + f2);
        h2 wv0 = *(const h2*)(wt + m0.y + f2);
        h2 xv1 = *(const h2*)(x + m1.x + f2);
        h2 wv1 = *(const h2*)(wt + m1.y + f2);
        ax += (float)xv0.x * (float)wv0.x;
        ay += (float)xv0.y * (float)wv0.y;
        ax += (float)xv1.x * (float)wv1.x;
        ay += (float)xv1.y * (float)wv1.y;
    }
    if (p < p1) {
        uint2 m0 = meta[p];
        h2 xv0 = *(const h2*)(x + m0.x + f2);
        h2 wv0 = *(const h2*)(wt + m0.y + f2);
        ax += (float)xv0.x * (float)wv0.x;
        ay += (float)xv0.y * (float)wv0.y;
    }
    if (half) {
        part[slot][ln] = make_float2(ax, ay);
    }
    __syncthreads();
    if (!half) {
        float2 o = part[slot][ln];
        *(float2*)&agg[((size_t)i << 7) + f2] = make_float2(ax + o.x, ay + o.y);
    }
}

// ---------------- readout ----------------

__global__ void mol_bounds(const int* __restrict__ a2c, const int* __restrict__ c2m,
                           int* __restrict__ ms, int* __restrict__ me) {
    int i = blockIdx.x * 256 + threadIdx.x;
    if (i >= NA) return;
    int m = c2m[a2c[i]];
    int mp = (i == 0) ? -1 : c2m[a2c[i - 1]];
    if (m != mp) ms[m] = i;
    int mn = (i == NA - 1) ? -1 : c2m[a2c[i + 1]];
    if (m != mn) me[m] = i + 1;
}

__global__ void mol_sum(const int* __restrict__ ms, const int* __restrict__ me,
                        const float* __restrict__ h2buf, float* __restrict__ mol) {
    int m = blockIdx.x, f = threadIdx.x;
    float acc = 0.f;
    int e0 = ms[m], e1 = me[m];
    for (int i = e0; i < e1; ++i) acc += h2buf[((size_t)i << 7) + f];
    mol[(m << 7) + f] = acc;
}

__global__ void final_mlp(const float* __restrict__ mol, const float* __restrict__ h1w,
                          const float* __restrict__ h1b, const float* __restrict__ h2w,
                          const float* __restrict__ h2b, float* __restrict__ out) {
    int m = blockIdx.x;
    int j = threadIdx.x;
    float acc = h1b[j];
    for (int k = 0; k < H; ++k) acc += mol[(m << 7) + k] * h1w[k * 64 + j];
    float hv = sspf(acc) * h2w[j];
    #pragma unroll
    for (int off = 32; off > 0; off >>= 1) hv += __shfl_down(hv, off);
    if (j == 0) out[m] = hv + h2b[0];
}

} // namespace

extern "C" void kernel_launch(void* const* d_in, const int* in_sizes, int n_in,
                              void* d_out, int out_size, void* d_ws, size_t ws_size,
                              hipStream_t stream) {
    const int*   z    = (const int*)d_in[0];
    const float* pos  = (const float*)d_in[1];
    const int*   ei   = (const int*)d_in[2];
    const int*   a2c  = (const int*)d_in[3];
    const int*   c2m  = (const int*)d_in[4];
    const float* emb  = (const float*)d_in[5];
    const float* iw1  = (const float*)d_in[6];
    const float* ib1  = (const float*)d_in[7];
    const float* iw2  = (const float*)d_in[8];
    const float* ib2  = (const float*)d_in[9];
    const float* il1  = (const float*)d_in[10];
    const float* il2w = (const float*)d_in[11];
    const float* il2b = (const float*)d_in[12];
    const float* ilw  = (const float*)d_in[13];
    const float* ilb  = (const float*)d_in[14];
    const float* l1w  = (const float*)d_in[15];
    const float* l1b  = (const float*)d_in[16];
    const float* l2w  = (const float*)d_in[17];
    const float* l2b  = (const float*)d_in[18];
    const float* h1w  = (const float*)d_in[19];
    const float* h1b  = (const float*)d_in[20];
    const float* h2w  = (const float*)d_in[21];
    const float* h2b  = (const float*)d_in[22];
    float* out = (float*)d_out;
    (void)in_sizes; (void)n_in; (void)out_size; (void)ws_size;

    char* base = (char*)d_ws;
    size_t off = 0;
    auto carve = [&](size_t bytes) -> char* {
        char* p = base + off;
        off += (bytes + 255) & ~(size_t)255;
        return p;
    };
    float*          h     = (float*)carve((size_t)NA * H * 4);
    unsigned short* xb    = (unsigned short*)carve((size_t)NA * H * 2);
    float*          agg   = (float*)carve((size_t)NA * H * 4);      // aliased as edge tmp below
    unsigned short* wtab  = (unsigned short*)carve((size_t)L * TBL * H * 2);
    uint2*          meta  = (uint2*)carve((size_t)NE * 8);
    int*            counts= (int*)carve((size_t)NA * 4);            // reused as cursor
    int*            rowp  = (int*)carve((size_t)(NA + 1) * 4);
    int*            bsum  = (int*)carve((size_t)NSCAN * 4);
    int*            ms    = (int*)carve((size_t)NM * 4);
    int*            me    = (int*)carve((size_t)NM * 4);
    float*          mol   = (float*)carve((size_t)NM * H * 4);
    unsigned short* il1t  = (unsigned short*)carve((size_t)L * H * H * 2);
    unsigned short* il2wt = (unsigned short*)carve((size_t)L * H * H * 2);
    unsigned short* ilwt  = (unsigned short*)carve((size_t)L * H * H * 2);
    unsigned short* l1wt  = (unsigned short*)carve((size_t)H * H * 2);
    unsigned short* l2wt  = (unsigned short*)carve((size_t)H * H * 2);

    // edge tmp arrays alias agg (dead before first edge_agg write)
    int* tt   = (int*)agg;
    int* ts   = tt + NE;
    int* tidx = ts + NE;

    hipMemsetAsync(counts, 0, (size_t)NA * 4, stream);
    edge_count<<<NE / 256, 256, 0, stream>>>(pos, ei, counts, tt, ts, tidx);
    scan_part<<<NSCAN, 256, 0, stream>>>(counts, bsum);
    scan_top<<<1, 256, 0, stream>>>(bsum, rowp);
    scan_write<<<NSCAN, 256, 0, stream>>>(counts, bsum, rowp);
    hipMemcpyAsync(counts, rowp, (size_t)NA * 4, hipMemcpyDeviceToDevice, stream);
    csr_fill<<<NE / 256, 256, 0, stream>>>(tt, ts, tidx, counts, meta);
    h_init<<<(NA * H) / 256, 256, 0, stream>>>(z, emb, h);

    convT<<<dim3(64, L), 256, 0, stream>>>(il1, il1t);
    convT<<<dim3(64, L), 256, 0, stream>>>(il2w, il2wt);
    convT<<<dim3(64, L), 256, 0, stream>>>(ilw, ilwt);
    convT<<<dim3(64, 1), 256, 0, stream>>>(l1w, l1wt);
    convT<<<dim3(64, 1), 256, 0, stream>>>(l2w, l2wt);
    build_table<<<dim3(TBL / 8, L), 128, 0, stream>>>(iw1, ib1, iw2, ib2, wtab);

    const int NG = (NA + 63) / 64;   // 782
    gemm_xonly<<<NG, 256, 0, stream>>>(h, il1t, xb, NA);
    for (int k = 0; k < L; ++k) {
        edge_agg<<<NA / 2, 256, 0, stream>>>(rowp, meta, xb, wtab + (size_t)k * TBL * H, agg);
        if (k < L - 1) {
            node_fused<1, 1><<<NG, 256, 0, stream>>>(agg, il2b + (size_t)k * H, il2wt + (size_t)k * H * H,
                                                     h, h, ilb + (size_t)k * H, ilwt + (size_t)k * H * H,
                                                     il1t + (size_t)(k + 1) * H * H, xb, NA);
        } else {
            node_fused<1, 0><<<NG, 256, 0, stream>>>(agg, il2b + (size_t)k * H, il2wt + (size_t)k * H * H,
                                                     h, h, ilb + (size_t)k * H, ilwt + (size_t)k * H * H,
                                                     nullptr, nullptr, NA);
        }
    }
    // final: agg = ssp(h@l1w+l1b)@l2w+l2b
    node_fused<0, 0><<<NG, 256, 0, stream>>>(h, l1b, l1wt, nullptr, agg, l2b, l2wt,
                                             nullptr, nullptr, NA);

    hipMemsetAsync(ms, 0, (size_t)NM * 4, stream);
    hipMemsetAsync(me, 0, (size_t)NM * 4, stream);
    mol_bounds<<<(NA + 255) / 256, 256, 0, stream>>>(a2c, c2m, ms, me);
    mol_sum<<<NM, 128, 0, stream>>>(ms, me, agg, mol);
    final_mlp<<<NM, 64, 0, stream>>>(mol, h1w, h1b, h2w, h2b, out);
}

// Round 4
// 916.621 us; speedup vs baseline: 1.9908x; 1.2889x over previous
//
#include <hip/hip_runtime.h>
#include <math.h>

namespace {

constexpr int NA  = 50000;
constexpr int NE  = 1600000;
constexpr int NM  = 500;
constexpr int H   = 128;
constexpr int G   = 50;
constexpr int L   = 6;
constexpr int TBL = 8192;
constexpr int PAD = 80;
constexpr float DMAX = 6.0f;

typedef _Float16 half8 __attribute__((ext_vector_type(8)));
typedef float f32x4 __attribute__((ext_vector_type(4)));
struct hpair { _Float16 x, y; };

__device__ __forceinline__ float sspf(float v) {
    return fmaxf(v, 0.0f) + log1pf(expf(-fabsf(v))) - 0.6931471805599453f;
}
__device__ __forceinline__ unsigned short f2h(float f) {
    _Float16 h = (_Float16)f;
    return __builtin_bit_cast(unsigned short, h);
}
__device__ __forceinline__ half8 cvt8(float4 a, float4 b) {
    half8 r;
    r[0] = (_Float16)a.x; r[1] = (_Float16)a.y; r[2] = (_Float16)a.z; r[3] = (_Float16)a.w;
    r[4] = (_Float16)b.x; r[5] = (_Float16)b.y; r[6] = (_Float16)b.z; r[7] = (_Float16)b.w;
    return r;
}
// B^T LDS granule offset with XOR swizzle (row stride 256B would be a wide conflict; G4)
__device__ __forceinline__ int bofs(int nrow, int g) {   // g = 16B granule 0..15, u16 index
    int gs = (g & 8) | ((g ^ nrow) & 7);
    return nrow * 128 + gs * 8;
}
__device__ __forceinline__ void stageB(const unsigned short* __restrict__ Bt,
                                       unsigned short* Bs, int tid) {
    for (int i = tid; i < 2048; i += 256) {
        int row = i >> 4, g = i & 15;
        *(uint4*)&Bs[bofs(row, g)] = *(const uint4*)&Bt[i * 8];
    }
}

// ---------------- preprocessing: one-pass padded-CSR build ----------------

__global__ void edge_build(const float* __restrict__ pos, const int* __restrict__ ei,
                           int* __restrict__ counts, unsigned* __restrict__ meta) {
    int e = blockIdx.x * 256 + threadIdx.x;
    if (e >= NE) return;
    int s = ei[e], t = ei[NE + e];
    float dx = pos[3*s]   - pos[3*t];
    float dy = pos[3*s+1] - pos[3*t+1];
    float dz = pos[3*s+2] - pos[3*t+2];
    float d = sqrtf(dx*dx + dy*dy + dz*dz + 1e-12f);
    float u = d * ((float)(TBL - 1) / DMAX);
    if (u < (float)(TBL - 1)) {
        int idx = (int)(u + 0.5f);
        int r = atomicAdd(&counts[t], 1);
        if (r < PAD) meta[(size_t)t * PAD + r] = (unsigned)s | ((unsigned)idx << 16);
    }
}

__global__ void h_init(const int* __restrict__ z, const float* __restrict__ emb,
                       float* __restrict__ h) {
    int idx = blockIdx.x * 256 + threadIdx.x;
    if (idx >= NA * H) return;
    int i = idx >> 7, f = idx & 127;
    h[idx] = emb[(z[i] << 7) + f];
}

// f32 [K][N] -> f16 B^T [N][K]
__global__ void convT(const float* __restrict__ src, unsigned short* __restrict__ dst) {
    int m = blockIdx.y;
    int e = blockIdx.x * 256 + threadIdx.x;   // e = n*128 + k
    int n = e >> 7, k = e & 127;
    dst[(size_t)m * 16384 + e] = f2h(src[(size_t)m * 16384 + k * 128 + n]);
}

// ---------------- filter tables: f16, nearest-sample, all layers ----------------

__global__ __launch_bounds__(128) void build_table(const float* __restrict__ iw1, const float* __restrict__ ib1,
                                                   const float* __restrict__ iw2, const float* __restrict__ ib2,
                                                   unsigned short* __restrict__ wtab) {
    int l = blockIdx.y;
    iw1 += (size_t)l * G * H; ib1 += (size_t)l * H;
    iw2 += (size_t)l * H * H; ib2 += (size_t)l * H;
    wtab += (size_t)l * TBL * H;
    __shared__ float ea[8][G];
    __shared__ float hid[8][H];
    int t0 = blockIdx.x * 8;
    int f = threadIdx.x;
    const float step  = DMAX / (float)(TBL - 1);
    const float sp    = 5.0f / 49.0f;
    const float coeff = -0.5f / (sp * sp);
    for (int idx = f; idx < 8 * G; idx += 128) {
        int r = idx / G, g = idx - r * G;
        float d = (float)(t0 + r) * step;
        float dd = d - (float)g * sp;
        ea[r][g] = expf(coeff * dd * dd);
    }
    __syncthreads();
    float acc[8];
    float b1 = ib1[f];
    #pragma unroll
    for (int r = 0; r < 8; ++r) acc[r] = b1;
    for (int g = 0; g < G; ++g) {
        float w = iw1[g * H + f];
        #pragma unroll
        for (int r = 0; r < 8; ++r) acc[r] += ea[r][g] * w;
    }
    #pragma unroll
    for (int r = 0; r < 8; ++r) hid[r][f] = sspf(acc[r]);
    __syncthreads();
    float o[8];
    float b2 = ib2[f];
    #pragma unroll
    for (int r = 0; r < 8; ++r) o[r] = b2;
    for (int j = 0; j < H; ++j) {
        float w = iw2[j * H + f];
        #pragma unroll
        for (int r = 0; r < 8; ++r) o[r] += hid[r][j] * w;
    }
    #pragma unroll
    for (int r = 0; r < 8; ++r) {
        float d = (float)(t0 + r) * step;
        float C = 0.5f * (cosf(d * (3.14159265358979323846f / 5.0f)) + 1.0f);
        wtab[(size_t)(t0 + r) * H + f] = f2h(o[r] * C);
    }
}

// ---------------- standalone x = f16(h @ B)  (layer 0 only) ----------------

__global__ __launch_bounds__(256) void gemm_xonly(const float* __restrict__ A,
                                                  const unsigned short* __restrict__ Bt,
                                                  unsigned short* __restrict__ xout, int M) {
    __shared__ unsigned short Bs[16384];
    int tid = threadIdx.x;
    int w = tid >> 6, lane = tid & 63, lr = lane & 15, lq = lane >> 4;
    int r0 = blockIdx.x * 64 + w * 16;
    stageB(Bt, Bs, tid);
    const float* arow = A + (size_t)min(r0 + lr, M - 1) * H;
    half8 af[4];
    #pragma unroll
    for (int ks = 0; ks < 4; ++ks)
        af[ks] = cvt8(*(const float4*)(arow + ks * 32 + lq * 8),
                      *(const float4*)(arow + ks * 32 + lq * 8 + 4));
    __syncthreads();
    #pragma unroll
    for (int n = 0; n < 8; ++n) {
        f32x4 acc = {0.f, 0.f, 0.f, 0.f};
        #pragma unroll
        for (int ks = 0; ks < 4; ++ks) {
            half8 bf = *(const half8*)&Bs[bofs(n * 16 + lr, ks * 4 + lq)];
            acc = __builtin_amdgcn_mfma_f32_16x16x32_f16(af[ks], bf, acc, 0, 0, 0);
        }
        #pragma unroll
        for (int j = 0; j < 4; ++j) {
            int row = r0 + 4 * lq + j;
            if (row < M) xout[(size_t)row * H + n * 16 + lr] = f2h(acc[j]);
        }
    }
}

// ---------------- fused node update ----------------
// pass A: t = ssp(Ain @ B1 + bias1)          (t -> LDS f16)
// pass B: hout = [hres +] t @ B2 + bias2     (and h f16 -> LDS if HASX)
// pass C: xout = f16(h @ B3)                 (if HASX)

template<int RES, int HASX, int AF16>
__global__ __launch_bounds__(256) void node_fused(const unsigned short* __restrict__ Ain16,
                                                  const float* __restrict__ Ain32,
                                                  const float* __restrict__ bias1,
                                                  const unsigned short* __restrict__ B1t,
                                                  const float* __restrict__ hres,
                                                  float* __restrict__ hout,
                                                  const float* __restrict__ bias2,
                                                  const unsigned short* __restrict__ B2t,
                                                  const unsigned short* __restrict__ B3t,
                                                  unsigned short* __restrict__ xout, int M) {
    __shared__ unsigned short Bs[16384];       // 32 KB, reused per pass
    __shared__ _Float16 Ts[64 * 136];          // 17 KB, t then h (f16)
    int tid = threadIdx.x;
    int w = tid >> 6, lane = tid & 63, lr = lane & 15, lq = lane >> 4;
    int r0 = blockIdx.x * 64 + w * 16;
    int trow = w * 16;

    stageB(B1t, Bs, tid);
    half8 af[4];
    if (AF16) {
        const unsigned short* arow = Ain16 + (size_t)min(r0 + lr, M - 1) * H;
        #pragma unroll
        for (int ks = 0; ks < 4; ++ks)
            af[ks] = *(const half8*)(arow + ks * 32 + lq * 8);
    } else {
        const float* arow = Ain32 + (size_t)min(r0 + lr, M - 1) * H;
        #pragma unroll
        for (int ks = 0; ks < 4; ++ks)
            af[ks] = cvt8(*(const float4*)(arow + ks * 32 + lq * 8),
                          *(const float4*)(arow + ks * 32 + lq * 8 + 4));
    }
    __syncthreads();

    // ---- pass A ----
    #pragma unroll
    for (int n = 0; n < 8; ++n) {
        f32x4 acc = {0.f, 0.f, 0.f, 0.f};
        #pragma unroll
        for (int ks = 0; ks < 4; ++ks) {
            half8 bf = *(const half8*)&Bs[bofs(n * 16 + lr, ks * 4 + lq)];
            acc = __builtin_amdgcn_mfma_f32_16x16x32_f16(af[ks], bf, acc, 0, 0, 0);
        }
        float b = bias1[n * 16 + lr];
        #pragma unroll
        for (int j = 0; j < 4; ++j)
            Ts[(trow + 4 * lq + j) * 136 + n * 16 + lr] = (_Float16)sspf(acc[j] + b);
    }
    __syncthreads();
    stageB(B2t, Bs, tid);
    half8 tf[4];
    #pragma unroll
    for (int ks = 0; ks < 4; ++ks)
        tf[ks] = *(const half8*)&Ts[(trow + lr) * 136 + ks * 32 + lq * 8];
    __syncthreads();

    // ---- pass B ----
    #pragma unroll
    for (int n = 0; n < 8; ++n) {
        f32x4 acc = {0.f, 0.f, 0.f, 0.f};
        #pragma unroll
        for (int ks = 0; ks < 4; ++ks) {
            half8 bf = *(const half8*)&Bs[bofs(n * 16 + lr, ks * 4 + lq)];
            acc = __builtin_amdgcn_mfma_f32_16x16x32_f16(tf[ks], bf, acc, 0, 0, 0);
        }
        float b = bias2[n * 16 + lr];
        #pragma unroll
        for (int j = 0; j < 4; ++j) {
            int row = r0 + 4 * lq + j;
            float v = acc[j] + b;
            if (RES) v += hres[(size_t)min(row, M - 1) * H + n * 16 + lr];
            if (row < M) hout[(size_t)row * H + n * 16 + lr] = v;
            if (HASX) Ts[(trow + 4 * lq + j) * 136 + n * 16 + lr] = (_Float16)v;
        }
    }

    // ---- pass C ----
    if (HASX) {
        __syncthreads();
        stageB(B3t, Bs, tid);
        half8 hf[4];
        #pragma unroll
        for (int ks = 0; ks < 4; ++ks)
            hf[ks] = *(const half8*)&Ts[(trow + lr) * 136 + ks * 32 + lq * 8];
        __syncthreads();
        #pragma unroll
        for (int n = 0; n < 8; ++n) {
            f32x4 acc = {0.f, 0.f, 0.f, 0.f};
            #pragma unroll
            for (int ks = 0; ks < 4; ++ks) {
                half8 bf = *(const half8*)&Bs[bofs(n * 16 + lr, ks * 4 + lq)];
                acc = __builtin_amdgcn_mfma_f32_16x16x32_f16(hf[ks], bf, acc, 0, 0, 0);
            }
            #pragma unroll
            for (int j = 0; j < 4; ++j) {
                int row = r0 + 4 * lq + j;
                if (row < M) xout[(size_t)row * H + n * 16 + lr] = f2h(acc[j]);
            }
        }
    }
}

// ---------------- edge aggregation: 1 wave/atom, 8-deep edge ILP, f16 out ----------------

__global__ __launch_bounds__(256) void edge_agg(const int* __restrict__ deg,
                                                const unsigned* __restrict__ meta,
                                                const unsigned short* __restrict__ x,
                                                const unsigned short* __restrict__ wt,
                                                unsigned short* __restrict__ agg) {
    int wv = threadIdx.x >> 6, ln = threadIdx.x & 63;
    int i = (blockIdx.x << 2) + wv;
    if (i >= NA) return;
    int n = min(deg[i], PAD);
    const unsigned* mrow = meta + (size_t)i * PAD;
    int f2 = ln << 1;
    float ax = 0.f, ay = 0.f;
    for (int p = 0; p < n; p += 8) {
        int rem = n - p;                      // wave-uniform
        unsigned mm[8];
        #pragma unroll
        for (int j = 0; j < 8; ++j) mm[j] = mrow[p + min(j, rem - 1)];
        unsigned xv[8], wvv[8];
        #pragma unroll
        for (int j = 0; j < 8; ++j) {
            unsigned s   = mm[j] & 0xFFFFu;
            unsigned idx = mm[j] >> 16;
            xv[j]  = *(const unsigned*)(x  + (s   << 7) + f2);
            wvv[j] = *(const unsigned*)(wt + (idx << 7) + f2);
        }
        #pragma unroll
        for (int j = 0; j < 8; ++j) {
            if (j < rem) {
                hpair xh = __builtin_bit_cast(hpair, xv[j]);
                hpair wh = __builtin_bit_cast(hpair, wvv[j]);
                ax += (float)xh.x * (float)wh.x;
                ay += (float)xh.y * (float)wh.y;
            }
        }
    }
    hpair o; o.x = (_Float16)ax; o.y = (_Float16)ay;
    *(unsigned*)&agg[((size_t)i << 7) + f2] = __builtin_bit_cast(unsigned, o);
}

// ---------------- readout ----------------

__global__ void mol_bounds(const int* __restrict__ a2c, const int* __restrict__ c2m,
                           int* __restrict__ ms, int* __restrict__ me) {
    int i = blockIdx.x * 256 + threadIdx.x;
    if (i >= NA) return;
    int m = c2m[a2c[i]];
    int mp = (i == 0) ? -1 : c2m[a2c[i - 1]];
    if (m != mp) ms[m] = i;
    int mn = (i == NA - 1) ? -1 : c2m[a2c[i + 1]];
    if (m != mn) me[m] = i + 1;
}

__global__ void mol_sum(const int* __restrict__ ms, const int* __restrict__ me,
                        const float* __restrict__ h2buf, float* __restrict__ mol) {
    int m = blockIdx.x, f = threadIdx.x;
    float acc = 0.f;
    int e0 = ms[m], e1 = me[m];
    for (int i = e0; i < e1; ++i) acc += h2buf[((size_t)i << 7) + f];
    mol[(m << 7) + f] = acc;
}

__global__ void final_mlp(const float* __restrict__ mol, const float* __restrict__ h1w,
                          const float* __restrict__ h1b, const float* __restrict__ h2w,
                          const float* __restrict__ h2b, float* __restrict__ out) {
    int m = blockIdx.x;
    int j = threadIdx.x;
    float acc = h1b[j];
    for (int k = 0; k < H; ++k) acc += mol[(m << 7) + k] * h1w[k * 64 + j];
    float hv = sspf(acc) * h2w[j];
    #pragma unroll
    for (int off = 32; off > 0; off >>= 1) hv += __shfl_down(hv, off);
    if (j == 0) out[m] = hv + h2b[0];
}

} // namespace

extern "C" void kernel_launch(void* const* d_in, const int* in_sizes, int n_in,
                              void* d_out, int out_size, void* d_ws, size_t ws_size,
                              hipStream_t stream) {
    const int*   z    = (const int*)d_in[0];
    const float* pos  = (const float*)d_in[1];
    const int*   ei   = (const int*)d_in[2];
    const int*   a2c  = (const int*)d_in[3];
    const int*   c2m  = (const int*)d_in[4];
    const float* emb  = (const float*)d_in[5];
    const float* iw1  = (const float*)d_in[6];
    const float* ib1  = (const float*)d_in[7];
    const float* iw2  = (const float*)d_in[8];
    const float* ib2  = (const float*)d_in[9];
    const float* il1  = (const float*)d_in[10];
    const float* il2w = (const float*)d_in[11];
    const float* il2b = (const float*)d_in[12];
    const float* ilw  = (const float*)d_in[13];
    const float* ilb  = (const float*)d_in[14];
    const float* l1w  = (const float*)d_in[15];
    const float* l1b  = (const float*)d_in[16];
    const float* l2w  = (const float*)d_in[17];
    const float* l2b  = (const float*)d_in[18];
    const float* h1w  = (const float*)d_in[19];
    const float* h1b  = (const float*)d_in[20];
    const float* h2w  = (const float*)d_in[21];
    const float* h2b  = (const float*)d_in[22];
    float* out = (float*)d_out;
    (void)in_sizes; (void)n_in; (void)out_size; (void)ws_size;

    char* base = (char*)d_ws;
    size_t off = 0;
    auto carve = [&](size_t bytes) -> char* {
        char* p = base + off;
        off += (bytes + 255) & ~(size_t)255;
        return p;
    };
    float*          h     = (float*)carve((size_t)NA * H * 4);
    unsigned short* xb    = (unsigned short*)carve((size_t)NA * H * 2);
    float*          agg   = (float*)carve((size_t)NA * H * 4);   // f16 during loop, f32 at end
    unsigned short* wtab  = (unsigned short*)carve((size_t)L * TBL * H * 2);
    unsigned*       meta  = (unsigned*)carve((size_t)NA * PAD * 4);
    int*            counts= (int*)carve((size_t)NA * 4);
    int*            ms    = (int*)carve((size_t)NM * 4);
    int*            me    = (int*)carve((size_t)NM * 4);
    float*          mol   = (float*)carve((size_t)NM * H * 4);
    unsigned short* il1t  = (unsigned short*)carve((size_t)L * H * H * 2);
    unsigned short* il2wt = (unsigned short*)carve((size_t)L * H * H * 2);
    unsigned short* ilwt  = (unsigned short*)carve((size_t)L * H * H * 2);
    unsigned short* l1wt  = (unsigned short*)carve((size_t)H * H * 2);
    unsigned short* l2wt  = (unsigned short*)carve((size_t)H * H * 2);
    unsigned short* aggh  = (unsigned short*)agg;

    hipMemsetAsync(counts, 0, (size_t)NA * 4, stream);
    edge_build<<<NE / 256, 256, 0, stream>>>(pos, ei, counts, meta);
    h_init<<<(NA * H) / 256, 256, 0, stream>>>(z, emb, h);

    convT<<<dim3(64, L), 256, 0, stream>>>(il1, il1t);
    convT<<<dim3(64, L), 256, 0, stream>>>(il2w, il2wt);
    convT<<<dim3(64, L), 256, 0, stream>>>(ilw, ilwt);
    convT<<<dim3(64, 1), 256, 0, stream>>>(l1w, l1wt);
    convT<<<dim3(64, 1), 256, 0, stream>>>(l2w, l2wt);
    build_table<<<dim3(TBL / 8, L), 128, 0, stream>>>(iw1, ib1, iw2, ib2, wtab);

    const int NG = (NA + 63) / 64;   // 782
    gemm_xonly<<<NG, 256, 0, stream>>>(h, il1t, xb, NA);
    for (int k = 0; k < L; ++k) {
        edge_agg<<<(NA + 3) / 4, 256, 0, stream>>>(counts, meta, xb,
                                                   wtab + (size_t)k * TBL * H, aggh);
        if (k < L - 1) {
            node_fused<1, 1, 1><<<NG, 256, 0, stream>>>(aggh, nullptr,
                il2b + (size_t)k * H, il2wt + (size_t)k * H * H,
                h, h, ilb + (size_t)k * H, ilwt + (size_t)k * H * H,
                il1t + (size_t)(k + 1) * H * H, xb, NA);
        } else {
            node_fused<1, 0, 1><<<NG, 256, 0, stream>>>(aggh, nullptr,
                il2b + (size_t)k * H, il2wt + (size_t)k * H * H,
                h, h, ilb + (size_t)k * H, ilwt + (size_t)k * H * H,
                nullptr, nullptr, NA);
        }
    }
    // final: agg(f32) = ssp(h@l1w+l1b)@l2w+l2b
    node_fused<0, 0, 0><<<NG, 256, 0, stream>>>(nullptr, h, l1b, l1wt, nullptr, agg,
                                                l2b, l2wt, nullptr, nullptr, NA);

    hipMemsetAsync(ms, 0, (size_t)NM * 4, stream);
    hipMemsetAsync(me, 0, (size_t)NM * 4, stream);
    mol_bounds<<<(NA + 255) / 256, 256, 0, stream>>>(a2c, c2m, ms, me);
    mol_sum<<<NM, 128, 0, stream>>>(ms, me, agg, mol);
    final_mlp<<<NM, 64, 0, stream>>>(mol, h1w, h1b, h2w, h2b, out);
}